// Round 6
// baseline (239.443 us; speedup 1.0000x reference)
//
#include <hip/hip_runtime.h>
#include <cstdint>
#include <type_traits>
#include <utility>

// ---------- types ----------
typedef __attribute__((ext_vector_type(8))) short short8;
typedef __attribute__((ext_vector_type(8))) _Float16 f16x8_t;
typedef __attribute__((ext_vector_type(4))) float f32x4;

// f16 frag (all matmuls run fp16 single-term: err ~2^-11 rel)
template <typename V, typename = void>
struct mfma_h_takes : std::false_type {};
template <typename V>
struct mfma_h_takes<V, std::void_t<decltype(__builtin_amdgcn_mfma_f32_16x16x32_f16(
    std::declval<V>(), std::declval<V>(), std::declval<f32x4>(), 0, 0, 0))>>
    : std::true_type {};

using hfrag_t = std::conditional_t<mfma_h_takes<f16x8_t>::value, f16x8_t, short8>;
static_assert(mfma_h_takes<f16x8_t>::value || mfma_h_takes<short8>::value,
              "no usable mfma_f32_16x16x32_f16 signature");

__device__ __forceinline__ f32x4 mfma16h(hfrag_t a, hfrag_t b, f32x4 c) {
  return __builtin_amdgcn_mfma_f32_16x16x32_f16(a, b, c, 0, 0, 0);
}

// ---------- async global->LDS, 16B per lane (m97 path) ----------
__device__ __forceinline__ void gld_lds16(const void* g, void* l) {
  __builtin_amdgcn_global_load_lds(
      (const __attribute__((address_space(1))) void*)(uintptr_t)g,
      (__attribute__((address_space(3))) void*)(uint32_t)(uintptr_t)l, 16, 0, 0);
}

// ---------- fp32 -> fp16 helpers (RNE via v_cvt_f16_f32) ----------
__device__ __forceinline__ uint16_t f16_rne(float x) {
  return __builtin_bit_cast(uint16_t, (_Float16)x);
}
__device__ __forceinline__ float f16_up(uint16_t h) {
  return (float)__builtin_bit_cast(_Float16, h);
}

__device__ __forceinline__ float exp2_fast(float x) {
#if __has_builtin(__builtin_amdgcn_exp2f)
  return __builtin_amdgcn_exp2f(x);
#else
  return exp2f(x);
#endif
}
__device__ __forceinline__ uint32_t pk_f16(float a, float b) {
#if __has_builtin(__builtin_amdgcn_cvt_pkrtz)
  return __builtin_bit_cast(uint32_t, __builtin_amdgcn_cvt_pkrtz(a, b));
#else
  union { uint16_t u[2]; uint32_t w; } r;
  r.u[0] = f16_rne(a);
  r.u[1] = f16_rne(b);
  return r.w;
#endif
}

// XOR-swizzled LDS index for 64-elem (128B) rows: conflict-free (r5-verified).
__device__ __forceinline__ int swz(int row, int col) {
  return row * 64 + ((((col >> 3) + row) & 7) << 3) + (col & 7);
}

// ---------- fused elementwise fp16 split pre-pass ----------
struct SplitArgs {
  const float* src[4];
  uint16_t* hi[4];
  uint16_t* lo[4];  // nullptr -> hi-only
  int n4;
};
__global__ void split_multi(SplitArgs a) {
  const int z = blockIdx.y;
  int i = blockIdx.x * 256 + threadIdx.x;
  if (i >= a.n4) return;
  float4 x = ((const float4*)a.src[z])[i];
  ushort4 h;
  h.x = f16_rne(x.x);
  h.y = f16_rne(x.y);
  h.z = f16_rne(x.z);
  h.w = f16_rne(x.w);
  ((ushort4*)a.hi[z])[i] = h;
  if (a.lo[z]) {
    ushort4 l;
    l.x = f16_rne(x.x - f16_up(h.x));
    l.y = f16_rne(x.y - f16_up(h.y));
    l.z = f16_rne(x.z - f16_up(h.z));
    l.w = f16_rne(x.w - f16_up(h.w));
    ((ushort4*)a.lo[z])[i] = l;
  }
}

// ---------- fused QKV projection GEMM, fp16, BK=64, SINGLE-buffer ----------
// R5 lesson: 64 KB dbuf dropped residency 3->2 blocks/CU (grid needs 3/CU)
// and cost +19 us. Single 32 KB buffer keeps 3 blocks/CU; implicit
// inter-block wave overlap (m114) does the latency hiding.
// 8-unit row permutation keeps ds_read_b128 conflict-free (R4: conflicts=0).
// z=0 epilogue pre-scales Q by 1/8*log2(e) so attn's exp2 needs no mul.
struct QKVArgs {
  const uint16_t* Ah[3];
  const uint16_t* Bh[3];
  const float* bias[3];
  uint16_t* oH[3];
  uint16_t* oL[3];  // nullptr -> hi-only
};

__global__ __launch_bounds__(256, 3) void gemm_qkv(QKVArgs args) {
  __shared__ uint16_t lds[2][128][64];  // A, B (32 KB)
  const int K = 1024;
  const int tid = threadIdx.x;
  const int wv = tid >> 6, lane = tid & 63;
  const int lm = lane & 15, g = lane >> 4;
  const int wm = (wv & 1) * 64, wn = (wv >> 1) * 64;
  const int z = blockIdx.z;
  const bool isT = (z == 2);
  const int t = blockIdx.x + 8 * blockIdx.y;
  const int kx = t & 7, j = t >> 3;
  const int sx = (j & 3) | ((kx & 1) << 2);
  const int sy = (j >> 2) | ((kx >> 1) << 3);
  const int gm0 = (isT ? sx : sy) * 128;
  const int gn0 = (isT ? sy : sx) * 128;

  const uint16_t* base[2] = {args.Ah[z] + (size_t)gm0 * K,
                             args.Bh[z] + (size_t)gn0 * K};
  const int rl8 = lane >> 3;                     // row within 8-row chunk
  const int scl = (((lane & 7) - rl8) & 7) * 8;  // pre-permuted src unit

  f32x4 acc[4][4];
#pragma unroll
  for (int a = 0; a < 4; ++a)
#pragma unroll
    for (int b = 0; b < 4; ++b) acc[a][b] = (f32x4)0.0f;

#pragma unroll 1
  for (int kt = 0; kt < K; kt += 64) {
    // 32 chunks of 1KB (8 rows x 128B); wave wv takes {wv, wv+4, ...}
#pragma unroll
    for (int jj = 0; jj < 8; ++jj) {
      const int c = wv + 4 * jj;
      const int p = c >> 4, r8 = (c & 15) * 8;
      gld_lds16(base[p] + (size_t)(r8 + rl8) * K + kt + scl, &lds[p][r8][0]);
    }
    __syncthreads();
#pragma unroll
    for (int ks = 0; ks < 2; ++ks) {
      const int uc = ((ks * 4 + g + lm) & 7) * 8;  // permuted read unit
      hfrag_t af[4];
#pragma unroll
      for (int mf = 0; mf < 4; ++mf) {
        af[mf] = *(const hfrag_t*)&lds[0][wm + mf * 16 + lm][uc];
      }
#pragma unroll
      for (int nf = 0; nf < 4; ++nf) {
        hfrag_t bhf = *(const hfrag_t*)&lds[1][wn + nf * 16 + lm][uc];
#pragma unroll
        for (int mf = 0; mf < 4; ++mf) {
          acc[mf][nf] = mfma16h(af[mf], bhf, acc[mf][nf]);
        }
      }
    }
    __syncthreads();
  }
  const float* bias = args.bias[z];
  uint16_t* oH = args.oH[z];
  uint16_t* oL = args.oL[z];
  const float kQScale = 0.18033688f;  // 1/8 * log2(e): pre-scale Q for exp2
#pragma unroll
  for (int mf = 0; mf < 4; ++mf) {
#pragma unroll
    for (int nf = 0; nf < 4; ++nf) {
      const int col = gn0 + wn + nf * 16 + lm;
#pragma unroll
      for (int i = 0; i < 4; ++i) {
        const int row = gm0 + wm + mf * 16 + g * 4 + i;
        float v = acc[mf][nf][i] + (isT ? bias[row] : bias[col]);
        if (z == 0) v *= kQScale;
        uint16_t h = f16_rne(v);
        size_t addr;
        if (!isT) {
          addr = ((size_t)((row >> 11) * 16 + (col >> 6)) * 2048 + (row & 2047)) * 64 +
                 (col & 63);
        } else {
          addr = ((size_t)((col >> 11) * 1024 + row)) * 2048 + (col & 2047);
        }
        oH[addr] = h;
        if (oL) oL[addr] = f16_rne(v - f16_up(h));
      }
    }
  }
}

// ---------- O projection: fp16, BK=64, double-buffered, fp32 out ----------
// dbuf kept here: grid is 2 blocks/CU and 2x48KB = 96KB fits -> no occupancy
// cost, counted vmcnt(6) keeps next tile's loads in flight across barriers.
__global__ __launch_bounds__(256, 2) void gemm_o(
    const uint16_t* __restrict__ Ah, const uint16_t* __restrict__ Bh,
    const float* __restrict__ bias, float* __restrict__ out) {
  const int K = 1024, N = 1024;
  __shared__ uint16_t ldsA[2][64][64];   // 16 KB
  __shared__ uint16_t ldsB[2][128][64];  // 32 KB
  const int tid = threadIdx.x;
  const int wv = tid >> 6, lane = tid & 63;
  const int lm = lane & 15, g = lane >> 4;
  const int wm = (wv & 1) * 32, wn = (wv >> 1) * 64;
  const int t = blockIdx.x + 8 * blockIdx.y;
  const int kx = t & 7, j = t >> 3;
  const int sx = (j & 3) | ((kx & 1) << 2);
  const int sy = (j >> 2) | ((kx >> 1) << 4);
  const int gm0 = sy * 64, gn0 = sx * 128;
  const uint16_t* baseA = Ah + (size_t)gm0 * K;
  const uint16_t* baseB = Bh + (size_t)gn0 * K;
  const int rl8 = lane >> 3;
  const int scl = (((lane & 7) - rl8) & 7) * 8;

  f32x4 acc[2][4];
#pragma unroll
  for (int a = 0; a < 2; ++a)
#pragma unroll
    for (int b = 0; b < 4; ++b) acc[a][b] = (f32x4)0.0f;

  // prologue: stage tile 0 into buf 0
#pragma unroll
  for (int jj = 0; jj < 6; ++jj) {
    const int c = wv + 4 * jj;  // 24 chunks: 8 A + 16 B
    if (c < 8) {
      gld_lds16(baseA + (size_t)(c * 8 + rl8) * K + 0 + scl, &ldsA[0][c * 8][0]);
    } else {
      const int b = c - 8;
      gld_lds16(baseB + (size_t)(b * 8 + rl8) * K + 0 + scl, &ldsB[0][b * 8][0]);
    }
  }

#pragma unroll 1
  for (int ti = 0; ti < 16; ++ti) {
    const int cur = ti & 1;
    if (ti + 1 < 16) {
      const int kt = (ti + 1) * 64;
#pragma unroll
      for (int jj = 0; jj < 6; ++jj) {
        const int c = wv + 4 * jj;
        if (c < 8) {
          gld_lds16(baseA + (size_t)(c * 8 + rl8) * K + kt + scl,
                    &ldsA[cur ^ 1][c * 8][0]);
        } else {
          const int b = c - 8;
          gld_lds16(baseB + (size_t)(b * 8 + rl8) * K + kt + scl,
                    &ldsB[cur ^ 1][b * 8][0]);
        }
      }
      asm volatile("s_waitcnt vmcnt(6)" ::: "memory");
    } else {
      asm volatile("s_waitcnt vmcnt(0)" ::: "memory");
    }
    __builtin_amdgcn_sched_barrier(0);
    __builtin_amdgcn_s_barrier();
    __builtin_amdgcn_sched_barrier(0);
#pragma unroll
    for (int ks = 0; ks < 2; ++ks) {
      const int uc = ((ks * 4 + g + lm) & 7) * 8;
      hfrag_t af[2];
#pragma unroll
      for (int mf = 0; mf < 2; ++mf) {
        af[mf] = *(const hfrag_t*)&ldsA[cur][wm + mf * 16 + lm][uc];
      }
#pragma unroll
      for (int nf = 0; nf < 4; ++nf) {
        hfrag_t bhf = *(const hfrag_t*)&ldsB[cur][wn + nf * 16 + lm][uc];
#pragma unroll
        for (int mf = 0; mf < 2; ++mf) {
          acc[mf][nf] = mfma16h(af[mf], bhf, acc[mf][nf]);
        }
      }
    }
    __builtin_amdgcn_sched_barrier(0);
    __builtin_amdgcn_s_barrier();
    __builtin_amdgcn_sched_barrier(0);
  }
#pragma unroll
  for (int mf = 0; mf < 2; ++mf)
#pragma unroll
    for (int nf = 0; nf < 4; ++nf) {
      const int col = gn0 + wn + nf * 16 + lm;
#pragma unroll
      for (int i = 0; i < 4; ++i) {
        const int row = gm0 + wm + mf * 16 + g * 4 + i;
        out[(size_t)row * N + col] = acc[mf][nf][i] + bias[col];
      }
    }
}

// ---------- fused attention v10: fp16 core; K prefetch at barrier-1 --------
// (K loads hide under QK^T + softmax + PV); exp2 scale folded into Q.
__global__ __launch_bounds__(256, 2) void attn_kernel(
    const uint16_t* __restrict__ Qh,
    const uint16_t* __restrict__ Kh,
    const uint16_t* __restrict__ Vh,
    float* __restrict__ opart, float* __restrict__ lpart) {
  __shared__ uint16_t kt[4096];  // K tile [kv 64][hd 64] hi, swizzled (8 KB)
  __shared__ uint16_t vt[4096];  // V^T tile [d 64][kv 64] hi, swizzled (8 KB)
  __shared__ uint16_t pp[8192];  // P (fp16) [qrow 128][kv 64], swizzled (16 KB)
  const int tid = threadIdx.x;
  const int wave = tid >> 6, lane = tid & 63;
  const int lm = lane & 15, g = lane >> 4;
  const int linear = blockIdx.x + 32 * blockIdx.y;
  const int bh = (linear & 7) + 8 * (linear >> 8);
  const int qt = (linear >> 3) & 15;
  const int half = (linear >> 7) & 1;
  const int kvh = half * 1024;
  const size_t base = (size_t)bh * 131072;
  const int q0 = qt * 128 + wave * 32;

  hfrag_t qf[2][2];  // [b(q-16-tile)][ks]  (Q pre-scaled by 1/8*log2(e))
#pragma unroll
  for (int b = 0; b < 2; ++b) {
    const size_t rb = base + (size_t)(q0 + b * 16 + lm) * 64 + g * 8;
    qf[b][0] = *(const hfrag_t*)(Qh + rb);
    qf[b][1] = *(const hfrag_t*)(Qh + rb + 32);
  }
  f32x4 oacc[2][4];
  f32x4 lacc[2];
#pragma unroll
  for (int mf = 0; mf < 2; ++mf) {
    lacc[mf] = (f32x4)0.0f;
#pragma unroll
    for (int nf = 0; nf < 4; ++nf) oacc[mf][nf] = (f32x4)0.0f;
  }
  short8 ones_s = (short8)(short)0x3C00;  // fp16 1.0
  hfrag_t ones = __builtin_bit_cast(hfrag_t, ones_s);

  const int sr = tid >> 3;       // 0..31
  const int sc = (tid & 7) * 8;  // 0..56

  uint4 kr0, kr1, vr0, vr1;
  {
    const size_t ka = base + (size_t)(kvh + sr) * 64 + sc;
    kr0 = *(const uint4*)(Kh + ka);
    kr1 = *(const uint4*)(Kh + ka + 2048);
  }

#pragma unroll 1
  for (int it = 0; it < 16; ++it) {
    const int kv0 = kvh + it * 64;
    *(uint4*)&kt[swz(sr, sc)] = kr0;
    *(uint4*)&kt[swz(sr + 32, sc)] = kr1;
    __syncthreads();  // barrier 1: K published; prev-iter vt reads done
    {  // issue V loads AND next-K loads; both hidden by QK^T+softmax+PV
      const size_t va = base + (size_t)sr * 2048 + kv0 + sc;
      vr0 = *(const uint4*)(Vh + va);
      vr1 = *(const uint4*)(Vh + va + 65536);
    }
    if (it + 1 < 16) {
      const size_t ka = base + (size_t)(kv0 + 64 + sr) * 64 + sc;
      kr0 = *(const uint4*)(Kh + ka);
      kr1 = *(const uint4*)(Kh + ka + 2048);
    }
    f32x4 sct[4][2];
#pragma unroll
    for (int a = 0; a < 4; ++a)
#pragma unroll
      for (int b = 0; b < 2; ++b) sct[a][b] = (f32x4)0.0f;
    __builtin_amdgcn_s_setprio(1);
#pragma unroll
    for (int ks = 0; ks < 2; ++ks) {
#pragma unroll
      for (int a = 0; a < 4; ++a) {
        hfrag_t kfh = *(const hfrag_t*)&kt[swz(a * 16 + lm, ks * 32 + g * 8)];
#pragma unroll
        for (int b = 0; b < 2; ++b) {
          sct[a][b] = mfma16h(kfh, qf[b][ks], sct[a][b]);
        }
      }
    }
    __builtin_amdgcn_s_setprio(0);
#pragma unroll
    for (int a = 0; a < 4; ++a) {
#pragma unroll
      for (int b = 0; b < 2; ++b) {
        // clamp arg so fp16 P can't overflow (exp2(15)=32768 < 65504)
        float e0 = exp2_fast(fminf(sct[a][b][0], 15.0f));
        float e1 = exp2_fast(fminf(sct[a][b][1], 15.0f));
        float e2 = exp2_fast(fminf(sct[a][b][2], 15.0f));
        float e3 = exp2_fast(fminf(sct[a][b][3], 15.0f));
        uint2 pk;
        pk.x = pk_f16(e0, e1);
        pk.y = pk_f16(e2, e3);
        *(uint2*)&pp[swz(wave * 32 + b * 16 + lm, a * 16 + g * 4)] = pk;
      }
    }
    *(uint4*)&vt[swz(sr, sc)] = vr0;
    *(uint4*)&vt[swz(sr + 32, sc)] = vr1;
    __syncthreads();  // barrier 2: V published; all waves' K reads done
    __builtin_amdgcn_s_setprio(1);
#pragma unroll
    for (int ks = 0; ks < 2; ++ks) {
      hfrag_t pa[2];
#pragma unroll
      for (int mf = 0; mf < 2; ++mf) {
        pa[mf] = *(const hfrag_t*)&pp[swz(wave * 32 + mf * 16 + lm, ks * 32 + g * 8)];
        lacc[mf] = mfma16h(pa[mf], ones, lacc[mf]);
      }
#pragma unroll
      for (int nf = 0; nf < 4; ++nf) {
        hfrag_t vbh = *(const hfrag_t*)&vt[swz(nf * 16 + lm, ks * 32 + g * 8)];
#pragma unroll
        for (int mf = 0; mf < 2; ++mf) {
          oacc[mf][nf] = mfma16h(pa[mf], vbh, oacc[mf][nf]);
        }
      }
    }
    __builtin_amdgcn_s_setprio(0);
  }
  const int obase = (half * 32 + bh) * 2048;
#pragma unroll
  for (int mf = 0; mf < 2; ++mf) {
#pragma unroll
    for (int i = 0; i < 4; ++i) {
      const int qrow = qt * 128 + wave * 32 + mf * 16 + g * 4 + i;
      float* orow = opart + ((size_t)obase + qrow) * 64;
#pragma unroll
      for (int nf = 0; nf < 4; ++nf) orow[nf * 16 + lm] = oacc[mf][nf][i];
      if (lm == 0) lpart[obase + qrow] = lacc[mf][i];
    }
  }
}

// ---------- combine partials, normalize, emit fp16 O plane ----------
__global__ void combine_kernel(const float* __restrict__ opart,
                               const float* __restrict__ lpart,
                               uint16_t* __restrict__ oh) {
  const int idx = blockIdx.x * 256 + threadIdx.x;
  const float4 a = ((const float4*)opart)[idx];
  const float4 b = ((const float4*)(opart + 4194304))[idx];
  const int row = idx >> 4;
  const float linv = 1.0f / (lpart[row] + lpart[65536 + row]);
  const int bh = row >> 11, qq = row & 2047;
  const int bb = bh >> 4, hh = bh & 15;
  const size_t o = ((size_t)(bb * 2048 + qq)) * 1024 + hh * 64 + (idx & 15) * 4;
  ushort4 H;
  H.x = f16_rne((a.x + b.x) * linv);
  H.y = f16_rne((a.y + b.y) * linv);
  H.z = f16_rne((a.z + b.z) * linv);
  H.w = f16_rne((a.w + b.w) * linv);
  *(ushort4*)(oh + o) = H;
}

extern "C" void kernel_launch(void* const* d_in, const int* in_sizes, int n_in,
                              void* d_out, int out_size, void* d_ws, size_t ws_size,
                              hipStream_t stream) {
  const float* q = (const float*)d_in[0];
  const float* k = (const float*)d_in[1];
  const float* v = (const float*)d_in[2];
  const float* Wq = (const float*)d_in[3];
  const float* bq = (const float*)d_in[4];
  const float* Wk = (const float*)d_in[5];
  const float* bk = (const float*)d_in[6];
  const float* Wv = (const float*)d_in[7];
  const float* bv = (const float*)d_in[8];
  const float* Wo = (const float*)d_in[9];
  const float* bo = (const float*)d_in[10];

  const size_t NX = 4194304;  // B*S*H
  const size_t NW = 1048576;  // H*H
  uint16_t* p = (uint16_t*)d_ws;
  uint16_t* xqh = p; p += NX; uint16_t* xql = p; p += NX;  // xql unused
  uint16_t* xkh = p; p += NX; uint16_t* xkl = p; p += NX;  // xkl unused
  uint16_t* xvh = p; p += NX; uint16_t* xvl = p; p += NX;  // xvl unused
  uint16_t* wqh = p; p += NW; uint16_t* wql = p; p += NW;  // wql unused
  uint16_t* wkh = p; p += NW; uint16_t* wkl = p; p += NW;  // wkl unused
  uint16_t* wvh = p; p += NW; uint16_t* wvl = p; p += NW;  // wvl unused
  uint16_t* woh = p; p += NW; uint16_t* wol = p; p += NW;  // wol unused
  uint16_t* qph = p; p += NX; uint16_t* qpl = p; p += NX;  // qpl unused
  uint16_t* kph = p; p += NX; uint16_t* kpl = p; p += NX;  // kpl unused
  uint16_t* vth = p; p += NX; uint16_t* vtl = p; p += NX;  // vtl unused
  uint16_t* oh = xqh;  // alias: xq consumed before combine writes o
  float* opart = (float*)xkh;          // 33.6 MB over xkh..xvl (dead after qkv)
  float* lpart = opart + 2 * 4194304;  // 0.5 MB into wq region (dead after qkv)

  SplitArgs sx;
  sx.src[0] = q;  sx.hi[0] = xqh; sx.lo[0] = nullptr;
  sx.src[1] = k;  sx.hi[1] = xkh; sx.lo[1] = nullptr;
  sx.src[2] = v;  sx.hi[2] = xvh; sx.lo[2] = nullptr;
  sx.src[3] = nullptr; sx.hi[3] = nullptr; sx.lo[3] = nullptr;
  sx.n4 = (int)(NX / 4);
  split_multi<<<dim3((unsigned)(NX / 4 / 256), 3), 256, 0, stream>>>(sx);

  SplitArgs sw;
  sw.src[0] = Wq; sw.hi[0] = wqh; sw.lo[0] = nullptr;
  sw.src[1] = Wk; sw.hi[1] = wkh; sw.lo[1] = nullptr;
  sw.src[2] = Wv; sw.hi[2] = wvh; sw.lo[2] = nullptr;
  sw.src[3] = Wo; sw.hi[3] = woh; sw.lo[3] = nullptr;
  sw.n4 = (int)(NW / 4);
  split_multi<<<dim3((unsigned)(NW / 4 / 256), 4), 256, 0, stream>>>(sw);

  QKVArgs qa;
  qa.Ah[0] = xqh; qa.Bh[0] = wqh; qa.bias[0] = bq; qa.oH[0] = qph; qa.oL[0] = nullptr;
  qa.Ah[1] = xkh; qa.Bh[1] = wkh; qa.bias[1] = bk; qa.oH[1] = kph; qa.oL[1] = nullptr;
  qa.Ah[2] = wvh; qa.Bh[2] = xvh; qa.bias[2] = bv; qa.oH[2] = vth; qa.oL[2] = nullptr;
  gemm_qkv<<<dim3(8, 32, 3), 256, 0, stream>>>(qa);

  attn_kernel<<<dim3(32, 32), 256, 0, stream>>>(qph, kph, vth, opart, lpart);
  combine_kernel<<<4096, 256, 0, stream>>>(opart, lpart, oh);

  gemm_o<<<dim3(8, 64), 256, 0, stream>>>(oh, woh, bo, (float*)d_out);
}

// Round 7
// 231.163 us; speedup vs baseline: 1.0358x; 1.0358x over previous
//
#include <hip/hip_runtime.h>
#include <cstdint>
#include <type_traits>
#include <utility>

// ---------- types ----------
typedef __attribute__((ext_vector_type(8))) short short8;
typedef __attribute__((ext_vector_type(8))) _Float16 f16x8_t;
typedef __attribute__((ext_vector_type(4))) float f32x4;

// f16 frag (all matmuls run fp16 single-term: err ~2^-11 rel)
template <typename V, typename = void>
struct mfma_h_takes : std::false_type {};
template <typename V>
struct mfma_h_takes<V, std::void_t<decltype(__builtin_amdgcn_mfma_f32_16x16x32_f16(
    std::declval<V>(), std::declval<V>(), std::declval<f32x4>(), 0, 0, 0))>>
    : std::true_type {};

using hfrag_t = std::conditional_t<mfma_h_takes<f16x8_t>::value, f16x8_t, short8>;
static_assert(mfma_h_takes<f16x8_t>::value || mfma_h_takes<short8>::value,
              "no usable mfma_f32_16x16x32_f16 signature");

__device__ __forceinline__ f32x4 mfma16h(hfrag_t a, hfrag_t b, f32x4 c) {
  return __builtin_amdgcn_mfma_f32_16x16x32_f16(a, b, c, 0, 0, 0);
}

// ---------- async global->LDS, 16B per lane (m97 path) ----------
__device__ __forceinline__ void gld_lds16(const void* g, void* l) {
  __builtin_amdgcn_global_load_lds(
      (const __attribute__((address_space(1))) void*)(uintptr_t)g,
      (__attribute__((address_space(3))) void*)(uint32_t)(uintptr_t)l, 16, 0, 0);
}

// ---------- fp32 -> fp16 helpers (RNE via v_cvt_f16_f32) ----------
__device__ __forceinline__ uint16_t f16_rne(float x) {
  return __builtin_bit_cast(uint16_t, (_Float16)x);
}
__device__ __forceinline__ float f16_up(uint16_t h) {
  return (float)__builtin_bit_cast(_Float16, h);
}

__device__ __forceinline__ float exp2_fast(float x) {
#if __has_builtin(__builtin_amdgcn_exp2f)
  return __builtin_amdgcn_exp2f(x);
#else
  return exp2f(x);
#endif
}
// v_cvt_pkrtz_f16_f32: round-toward-zero => overflow SATURATES to 65504
// (never inf) -- this makes an explicit pre-clamp unnecessary.
__device__ __forceinline__ uint32_t pk_f16(float a, float b) {
#if __has_builtin(__builtin_amdgcn_cvt_pkrtz)
  return __builtin_bit_cast(uint32_t, __builtin_amdgcn_cvt_pkrtz(a, b));
#else
  union { uint16_t u[2]; uint32_t w; } r;
  r.u[0] = f16_rne(fminf(a, 65504.0f));
  r.u[1] = f16_rne(fminf(b, 65504.0f));
  return r.w;
#endif
}

// XOR-swizzled LDS index for 64-elem (128B) rows: conflict-free (r5-verified).
__device__ __forceinline__ int swz(int row, int col) {
  return row * 64 + ((((col >> 3) + row) & 7) << 3) + (col & 7);
}

// ---------- fused elementwise fp16 split pre-pass ----------
struct SplitArgs {
  const float* src[4];
  uint16_t* hi[4];
  uint16_t* lo[4];  // nullptr -> hi-only
  int n4;
};
__global__ void split_multi(SplitArgs a) {
  const int z = blockIdx.y;
  int i = blockIdx.x * 256 + threadIdx.x;
  if (i >= a.n4) return;
  float4 x = ((const float4*)a.src[z])[i];
  ushort4 h;
  h.x = f16_rne(x.x);
  h.y = f16_rne(x.y);
  h.z = f16_rne(x.z);
  h.w = f16_rne(x.w);
  ((ushort4*)a.hi[z])[i] = h;
  if (a.lo[z]) {
    ushort4 l;
    l.x = f16_rne(x.x - f16_up(h.x));
    l.y = f16_rne(x.y - f16_up(h.y));
    l.z = f16_rne(x.z - f16_up(h.z));
    l.w = f16_rne(x.w - f16_up(h.w));
    ((ushort4*)a.lo[z])[i] = l;
  }
}

// ---------- fused QKV projection GEMM, fp16, BK=32, DBUF 32KB -------------
// R5 lesson: dbuf must not cost a residency slot. BK=32 tiles are 16KB ->
// 2x16=32KB dbuf keeps 3 blocks/CU (96KB < 160KB). Counted vmcnt(4) keeps
// the next tile's 4 loads/wave in flight across the barrier (T3/T4);
// vmcnt(0) only on the last K-step. 4-unit row permutation = R3-verified
// conflict-free (SQ_LDS_BANK_CONFLICT == 0).
// z=0 epilogue pre-scales Q by 1/8*log2(e) so attn's exp2 needs no mul.
struct QKVArgs {
  const uint16_t* Ah[3];
  const uint16_t* Bh[3];
  const float* bias[3];
  uint16_t* oH[3];
  uint16_t* oL[3];  // nullptr -> hi-only
};

__global__ __launch_bounds__(256, 3) void gemm_qkv(QKVArgs args) {
  __shared__ uint16_t lds[2][2][128][32];  // [dbuf][A/B] (32 KB)
  const int K = 1024;
  const int tid = threadIdx.x;
  const int wv = tid >> 6, lane = tid & 63;
  const int lm = lane & 15, g = lane >> 4;
  const int wm = (wv & 1) * 64, wn = (wv >> 1) * 64;
  const int z = blockIdx.z;
  const bool isT = (z == 2);
  const int t = blockIdx.x + 8 * blockIdx.y;
  const int kx = t & 7, j = t >> 3;
  const int sx = (j & 3) | ((kx & 1) << 2);
  const int sy = (j >> 2) | ((kx >> 1) << 3);
  const int gm0 = (isT ? sx : sy) * 128;
  const int gn0 = (isT ? sy : sx) * 128;

  const uint16_t* base[2] = {args.Ah[z] + (size_t)gm0 * K,
                             args.Bh[z] + (size_t)gn0 * K};
  const int rl = lane >> 2;                            // row within 16-row chunk
  const int scl = (((lane & 3) - (rl >> 1)) & 3) * 8;  // staging source unit
  const int ucol = ((g + (lm >> 1)) & 3) * 8;          // frag read unit

  f32x4 acc[4][4];
#pragma unroll
  for (int a = 0; a < 4; ++a)
#pragma unroll
    for (int b = 0; b < 4; ++b) acc[a][b] = (f32x4)0.0f;

  // prologue: stage K-step 0 into buf 0 (16 chunks of 1KB; 4 per wave)
#pragma unroll
  for (int jj = 0; jj < 4; ++jj) {
    const int c = wv + 4 * jj;
    const int p = c >> 3, r16 = (c & 7) * 16;
    gld_lds16(base[p] + (size_t)(r16 + rl) * K + 0 + scl, &lds[0][p][r16][0]);
  }

#pragma unroll 1
  for (int ti = 0; ti < 32; ++ti) {
    const int cur = ti & 1;
    if (ti + 1 < 32) {
      const int kt = (ti + 1) * 32;
#pragma unroll
      for (int jj = 0; jj < 4; ++jj) {
        const int c = wv + 4 * jj;
        const int p = c >> 3, r16 = (c & 7) * 16;
        gld_lds16(base[p] + (size_t)(r16 + rl) * K + kt + scl,
                  &lds[cur ^ 1][p][r16][0]);
      }
      asm volatile("s_waitcnt vmcnt(4)" ::: "memory");
    } else {
      asm volatile("s_waitcnt vmcnt(0)" ::: "memory");
    }
    __builtin_amdgcn_sched_barrier(0);
    __builtin_amdgcn_s_barrier();
    __builtin_amdgcn_sched_barrier(0);
    hfrag_t af[4];
#pragma unroll
    for (int mf = 0; mf < 4; ++mf) {
      af[mf] = *(const hfrag_t*)&lds[cur][0][wm + mf * 16 + lm][ucol];
    }
#pragma unroll
    for (int nf = 0; nf < 4; ++nf) {
      hfrag_t bhf = *(const hfrag_t*)&lds[cur][1][wn + nf * 16 + lm][ucol];
#pragma unroll
      for (int mf = 0; mf < 4; ++mf) {
        acc[mf][nf] = mfma16h(af[mf], bhf, acc[mf][nf]);
      }
    }
    __builtin_amdgcn_sched_barrier(0);
    __builtin_amdgcn_s_barrier();
    __builtin_amdgcn_sched_barrier(0);
  }
  const float* bias = args.bias[z];
  uint16_t* oH = args.oH[z];
  uint16_t* oL = args.oL[z];
  const float kQScale = 0.18033688f;  // 1/8 * log2(e): pre-scale Q for exp2
#pragma unroll
  for (int mf = 0; mf < 4; ++mf) {
#pragma unroll
    for (int nf = 0; nf < 4; ++nf) {
      const int col = gn0 + wn + nf * 16 + lm;
#pragma unroll
      for (int i = 0; i < 4; ++i) {
        const int row = gm0 + wm + mf * 16 + g * 4 + i;
        float v = acc[mf][nf][i] + (isT ? bias[row] : bias[col]);
        if (z == 0) v *= kQScale;
        uint16_t h = f16_rne(v);
        size_t addr;
        if (!isT) {
          addr = ((size_t)((row >> 11) * 16 + (col >> 6)) * 2048 + (row & 2047)) * 64 +
                 (col & 63);
        } else {
          addr = ((size_t)((col >> 11) * 1024 + row)) * 2048 + (col & 2047);
        }
        oH[addr] = h;
        if (oL) oL[addr] = f16_rne(v - f16_up(h));
      }
    }
  }
}

// ---------- O projection: fp16, BK=64, double-buffered, fp32 out ----------
// dbuf kept here: grid is 2 blocks/CU and 2x48KB = 96KB fits -> no occupancy
// cost, counted vmcnt(6) keeps next tile's loads in flight across barriers.
__global__ __launch_bounds__(256, 2) void gemm_o(
    const uint16_t* __restrict__ Ah, const uint16_t* __restrict__ Bh,
    const float* __restrict__ bias, float* __restrict__ out) {
  const int K = 1024, N = 1024;
  __shared__ uint16_t ldsA[2][64][64];   // 16 KB
  __shared__ uint16_t ldsB[2][128][64];  // 32 KB
  const int tid = threadIdx.x;
  const int wv = tid >> 6, lane = tid & 63;
  const int lm = lane & 15, g = lane >> 4;
  const int wm = (wv & 1) * 32, wn = (wv >> 1) * 64;
  const int t = blockIdx.x + 8 * blockIdx.y;
  const int kx = t & 7, j = t >> 3;
  const int sx = (j & 3) | ((kx & 1) << 2);
  const int sy = (j >> 2) | ((kx >> 1) << 4);
  const int gm0 = sy * 64, gn0 = sx * 128;
  const uint16_t* baseA = Ah + (size_t)gm0 * K;
  const uint16_t* baseB = Bh + (size_t)gn0 * K;
  const int rl8 = lane >> 3;
  const int scl = (((lane & 7) - rl8) & 7) * 8;

  f32x4 acc[2][4];
#pragma unroll
  for (int a = 0; a < 2; ++a)
#pragma unroll
    for (int b = 0; b < 4; ++b) acc[a][b] = (f32x4)0.0f;

  // prologue: stage tile 0 into buf 0
#pragma unroll
  for (int jj = 0; jj < 6; ++jj) {
    const int c = wv + 4 * jj;  // 24 chunks: 8 A + 16 B
    if (c < 8) {
      gld_lds16(baseA + (size_t)(c * 8 + rl8) * K + 0 + scl, &ldsA[0][c * 8][0]);
    } else {
      const int b = c - 8;
      gld_lds16(baseB + (size_t)(b * 8 + rl8) * K + 0 + scl, &ldsB[0][b * 8][0]);
    }
  }

#pragma unroll 1
  for (int ti = 0; ti < 16; ++ti) {
    const int cur = ti & 1;
    if (ti + 1 < 16) {
      const int kt = (ti + 1) * 64;
#pragma unroll
      for (int jj = 0; jj < 6; ++jj) {
        const int c = wv + 4 * jj;
        if (c < 8) {
          gld_lds16(baseA + (size_t)(c * 8 + rl8) * K + kt + scl,
                    &ldsA[cur ^ 1][c * 8][0]);
        } else {
          const int b = c - 8;
          gld_lds16(baseB + (size_t)(b * 8 + rl8) * K + kt + scl,
                    &ldsB[cur ^ 1][b * 8][0]);
        }
      }
      asm volatile("s_waitcnt vmcnt(6)" ::: "memory");
    } else {
      asm volatile("s_waitcnt vmcnt(0)" ::: "memory");
    }
    __builtin_amdgcn_sched_barrier(0);
    __builtin_amdgcn_s_barrier();
    __builtin_amdgcn_sched_barrier(0);
#pragma unroll
    for (int ks = 0; ks < 2; ++ks) {
      const int uc = ((ks * 4 + g + lm) & 7) * 8;
      hfrag_t af[2];
#pragma unroll
      for (int mf = 0; mf < 2; ++mf) {
        af[mf] = *(const hfrag_t*)&ldsA[cur][wm + mf * 16 + lm][uc];
      }
#pragma unroll
      for (int nf = 0; nf < 4; ++nf) {
        hfrag_t bhf = *(const hfrag_t*)&ldsB[cur][wn + nf * 16 + lm][uc];
#pragma unroll
        for (int mf = 0; mf < 2; ++mf) {
          acc[mf][nf] = mfma16h(af[mf], bhf, acc[mf][nf]);
        }
      }
    }
    __builtin_amdgcn_sched_barrier(0);
    __builtin_amdgcn_s_barrier();
    __builtin_amdgcn_sched_barrier(0);
  }
#pragma unroll
  for (int mf = 0; mf < 2; ++mf)
#pragma unroll
    for (int nf = 0; nf < 4; ++nf) {
      const int col = gn0 + wn + nf * 16 + lm;
#pragma unroll
      for (int i = 0; i < 4; ++i) {
        const int row = gm0 + wm + mf * 16 + g * 4 + i;
        out[(size_t)row * N + col] = acc[mf][nf][i] + bias[col];
      }
    }
}

// ---------- fused attention v11: fp16 core; no P clamp (pkrtz saturates) ---
__global__ __launch_bounds__(256, 2) void attn_kernel(
    const uint16_t* __restrict__ Qh,
    const uint16_t* __restrict__ Kh,
    const uint16_t* __restrict__ Vh,
    float* __restrict__ opart, float* __restrict__ lpart) {
  __shared__ uint16_t kt[4096];  // K tile [kv 64][hd 64] hi, swizzled (8 KB)
  __shared__ uint16_t vt[4096];  // V^T tile [d 64][kv 64] hi, swizzled (8 KB)
  __shared__ uint16_t pp[8192];  // P (fp16) [qrow 128][kv 64], swizzled (16 KB)
  const int tid = threadIdx.x;
  const int wave = tid >> 6, lane = tid & 63;
  const int lm = lane & 15, g = lane >> 4;
  const int linear = blockIdx.x + 32 * blockIdx.y;
  const int bh = (linear & 7) + 8 * (linear >> 8);
  const int qt = (linear >> 3) & 15;
  const int half = (linear >> 7) & 1;
  const int kvh = half * 1024;
  const size_t base = (size_t)bh * 131072;
  const int q0 = qt * 128 + wave * 32;

  hfrag_t qf[2][2];  // [b(q-16-tile)][ks]  (Q pre-scaled by 1/8*log2(e))
#pragma unroll
  for (int b = 0; b < 2; ++b) {
    const size_t rb = base + (size_t)(q0 + b * 16 + lm) * 64 + g * 8;
    qf[b][0] = *(const hfrag_t*)(Qh + rb);
    qf[b][1] = *(const hfrag_t*)(Qh + rb + 32);
  }
  f32x4 oacc[2][4];
  f32x4 lacc[2];
#pragma unroll
  for (int mf = 0; mf < 2; ++mf) {
    lacc[mf] = (f32x4)0.0f;
#pragma unroll
    for (int nf = 0; nf < 4; ++nf) oacc[mf][nf] = (f32x4)0.0f;
  }
  short8 ones_s = (short8)(short)0x3C00;  // fp16 1.0
  hfrag_t ones = __builtin_bit_cast(hfrag_t, ones_s);

  const int sr = tid >> 3;       // 0..31
  const int sc = (tid & 7) * 8;  // 0..56

  uint4 kr0, kr1, vr0, vr1;
  {
    const size_t ka = base + (size_t)(kvh + sr) * 64 + sc;
    kr0 = *(const uint4*)(Kh + ka);
    kr1 = *(const uint4*)(Kh + ka + 2048);
  }

#pragma unroll 1
  for (int it = 0; it < 16; ++it) {
    const int kv0 = kvh + it * 64;
    *(uint4*)&kt[swz(sr, sc)] = kr0;
    *(uint4*)&kt[swz(sr + 32, sc)] = kr1;
    __syncthreads();  // barrier 1: K published; prev-iter vt reads done
    {  // issue V loads AND next-K loads; both hidden by QK^T+softmax+PV
      const size_t va = base + (size_t)sr * 2048 + kv0 + sc;
      vr0 = *(const uint4*)(Vh + va);
      vr1 = *(const uint4*)(Vh + va + 65536);
    }
    if (it + 1 < 16) {
      const size_t ka = base + (size_t)(kv0 + 64 + sr) * 64 + sc;
      kr0 = *(const uint4*)(Kh + ka);
      kr1 = *(const uint4*)(Kh + ka + 2048);
    }
    f32x4 sct[4][2];
#pragma unroll
    for (int a = 0; a < 4; ++a)
#pragma unroll
      for (int b = 0; b < 2; ++b) sct[a][b] = (f32x4)0.0f;
    __builtin_amdgcn_s_setprio(1);
#pragma unroll
    for (int ks = 0; ks < 2; ++ks) {
#pragma unroll
      for (int a = 0; a < 4; ++a) {
        hfrag_t kfh = *(const hfrag_t*)&kt[swz(a * 16 + lm, ks * 32 + g * 8)];
#pragma unroll
        for (int b = 0; b < 2; ++b) {
          sct[a][b] = mfma16h(kfh, qf[b][ks], sct[a][b]);
        }
      }
    }
    __builtin_amdgcn_s_setprio(0);
#pragma unroll
    for (int a = 0; a < 4; ++a) {
#pragma unroll
      for (int b = 0; b < 2; ++b) {
        // no clamp: cvt_pkrtz saturates on overflow (RTZ -> 65504, not inf)
        float e0 = exp2_fast(sct[a][b][0]);
        float e1 = exp2_fast(sct[a][b][1]);
        float e2 = exp2_fast(sct[a][b][2]);
        float e3 = exp2_fast(sct[a][b][3]);
        uint2 pk;
        pk.x = pk_f16(e0, e1);
        pk.y = pk_f16(e2, e3);
        *(uint2*)&pp[swz(wave * 32 + b * 16 + lm, a * 16 + g * 4)] = pk;
      }
    }
    *(uint4*)&vt[swz(sr, sc)] = vr0;
    *(uint4*)&vt[swz(sr + 32, sc)] = vr1;
    __syncthreads();  // barrier 2: V published; all waves' K reads done
    __builtin_amdgcn_s_setprio(1);
#pragma unroll
    for (int ks = 0; ks < 2; ++ks) {
      hfrag_t pa[2];
#pragma unroll
      for (int mf = 0; mf < 2; ++mf) {
        pa[mf] = *(const hfrag_t*)&pp[swz(wave * 32 + mf * 16 + lm, ks * 32 + g * 8)];
        lacc[mf] = mfma16h(pa[mf], ones, lacc[mf]);
      }
#pragma unroll
      for (int nf = 0; nf < 4; ++nf) {
        hfrag_t vbh = *(const hfrag_t*)&vt[swz(nf * 16 + lm, ks * 32 + g * 8)];
#pragma unroll
        for (int mf = 0; mf < 2; ++mf) {
          oacc[mf][nf] = mfma16h(pa[mf], vbh, oacc[mf][nf]);
        }
      }
    }
    __builtin_amdgcn_s_setprio(0);
  }
  const int obase = (half * 32 + bh) * 2048;
#pragma unroll
  for (int mf = 0; mf < 2; ++mf) {
#pragma unroll
    for (int i = 0; i < 4; ++i) {
      const int qrow = qt * 128 + wave * 32 + mf * 16 + g * 4 + i;
      float* orow = opart + ((size_t)obase + qrow) * 64;
#pragma unroll
      for (int nf = 0; nf < 4; ++nf) orow[nf * 16 + lm] = oacc[mf][nf][i];
      if (lm == 0) lpart[obase + qrow] = lacc[mf][i];
    }
  }
}

// ---------- combine partials, normalize, emit fp16 O plane ----------
__global__ void combine_kernel(const float* __restrict__ opart,
                               const float* __restrict__ lpart,
                               uint16_t* __restrict__ oh) {
  const int idx = blockIdx.x * 256 + threadIdx.x;
  const float4 a = ((const float4*)opart)[idx];
  const float4 b = ((const float4*)(opart + 4194304))[idx];
  const int row = idx >> 4;
  const float linv = 1.0f / (lpart[row] + lpart[65536 + row]);
  const int bh = row >> 11, qq = row & 2047;
  const int bb = bh >> 4, hh = bh & 15;
  const size_t o = ((size_t)(bb * 2048 + qq)) * 1024 + hh * 64 + (idx & 15) * 4;
  ushort4 H;
  H.x = f16_rne((a.x + b.x) * linv);
  H.y = f16_rne((a.y + b.y) * linv);
  H.z = f16_rne((a.z + b.z) * linv);
  H.w = f16_rne((a.w + b.w) * linv);
  *(ushort4*)(oh + o) = H;
}

extern "C" void kernel_launch(void* const* d_in, const int* in_sizes, int n_in,
                              void* d_out, int out_size, void* d_ws, size_t ws_size,
                              hipStream_t stream) {
  const float* q = (const float*)d_in[0];
  const float* k = (const float*)d_in[1];
  const float* v = (const float*)d_in[2];
  const float* Wq = (const float*)d_in[3];
  const float* bq = (const float*)d_in[4];
  const float* Wk = (const float*)d_in[5];
  const float* bk = (const float*)d_in[6];
  const float* Wv = (const float*)d_in[7];
  const float* bv = (const float*)d_in[8];
  const float* Wo = (const float*)d_in[9];
  const float* bo = (const float*)d_in[10];

  const size_t NX = 4194304;  // B*S*H
  const size_t NW = 1048576;  // H*H
  uint16_t* p = (uint16_t*)d_ws;
  uint16_t* xqh = p; p += NX; uint16_t* xql = p; p += NX;  // xql unused
  uint16_t* xkh = p; p += NX; uint16_t* xkl = p; p += NX;  // xkl unused
  uint16_t* xvh = p; p += NX; uint16_t* xvl = p; p += NX;  // xvl unused
  uint16_t* wqh = p; p += NW; uint16_t* wql = p; p += NW;  // wql unused
  uint16_t* wkh = p; p += NW; uint16_t* wkl = p; p += NW;  // wkl unused
  uint16_t* wvh = p; p += NW; uint16_t* wvl = p; p += NW;  // wvl unused
  uint16_t* woh = p; p += NW; uint16_t* wol = p; p += NW;  // wol unused
  uint16_t* qph = p; p += NX; uint16_t* qpl = p; p += NX;  // qpl unused
  uint16_t* kph = p; p += NX; uint16_t* kpl = p; p += NX;  // kpl unused
  uint16_t* vth = p; p += NX; uint16_t* vtl = p; p += NX;  // vtl unused
  uint16_t* oh = xqh;  // alias: xq consumed before combine writes o
  float* opart = (float*)xkh;          // 33.6 MB over xkh..xvl (dead after qkv)
  float* lpart = opart + 2 * 4194304;  // 0.5 MB into wq region (dead after qkv)

  SplitArgs sx;
  sx.src[0] = q;  sx.hi[0] = xqh; sx.lo[0] = nullptr;
  sx.src[1] = k;  sx.hi[1] = xkh; sx.lo[1] = nullptr;
  sx.src[2] = v;  sx.hi[2] = xvh; sx.lo[2] = nullptr;
  sx.src[3] = nullptr; sx.hi[3] = nullptr; sx.lo[3] = nullptr;
  sx.n4 = (int)(NX / 4);
  split_multi<<<dim3((unsigned)(NX / 4 / 256), 3), 256, 0, stream>>>(sx);

  SplitArgs sw;
  sw.src[0] = Wq; sw.hi[0] = wqh; sw.lo[0] = nullptr;
  sw.src[1] = Wk; sw.hi[1] = wkh; sw.lo[1] = nullptr;
  sw.src[2] = Wv; sw.hi[2] = wvh; sw.lo[2] = nullptr;
  sw.src[3] = Wo; sw.hi[3] = woh; sw.lo[3] = nullptr;
  sw.n4 = (int)(NW / 4);
  split_multi<<<dim3((unsigned)(NW / 4 / 256), 4), 256, 0, stream>>>(sw);

  QKVArgs qa;
  qa.Ah[0] = xqh; qa.Bh[0] = wqh; qa.bias[0] = bq; qa.oH[0] = qph; qa.oL[0] = nullptr;
  qa.Ah[1] = xkh; qa.Bh[1] = wkh; qa.bias[1] = bk; qa.oH[1] = kph; qa.oL[1] = nullptr;
  qa.Ah[2] = wvh; qa.Bh[2] = xvh; qa.bias[2] = bv; qa.oH[2] = vth; qa.oL[2] = nullptr;
  gemm_qkv<<<dim3(8, 32, 3), 256, 0, stream>>>(qa);

  attn_kernel<<<dim3(32, 32), 256, 0, stream>>>(qph, kph, vth, opart, lpart);
  combine_kernel<<<4096, 256, 0, stream>>>(opart, lpart, oh);

  gemm_o<<<dim3(8, 64), 256, 0, stream>>>(oh, woh, bo, (float*)d_out);
}

// Round 8
// 230.111 us; speedup vs baseline: 1.0406x; 1.0046x over previous
//
#include <hip/hip_runtime.h>
#include <cstdint>
#include <type_traits>
#include <utility>

// ---------- types ----------
typedef __attribute__((ext_vector_type(8))) short short8;
typedef __attribute__((ext_vector_type(8))) _Float16 f16x8_t;
typedef __attribute__((ext_vector_type(4))) float f32x4;

// f16 frag (all matmuls run fp16 single-term: err ~2^-11 rel)
template <typename V, typename = void>
struct mfma_h_takes : std::false_type {};
template <typename V>
struct mfma_h_takes<V, std::void_t<decltype(__builtin_amdgcn_mfma_f32_16x16x32_f16(
    std::declval<V>(), std::declval<V>(), std::declval<f32x4>(), 0, 0, 0))>>
    : std::true_type {};

using hfrag_t = std::conditional_t<mfma_h_takes<f16x8_t>::value, f16x8_t, short8>;
static_assert(mfma_h_takes<f16x8_t>::value || mfma_h_takes<short8>::value,
              "no usable mfma_f32_16x16x32_f16 signature");

__device__ __forceinline__ f32x4 mfma16h(hfrag_t a, hfrag_t b, f32x4 c) {
  return __builtin_amdgcn_mfma_f32_16x16x32_f16(a, b, c, 0, 0, 0);
}

// ---------- async global->LDS, 16B per lane (m97 path) ----------
__device__ __forceinline__ void gld_lds16(const void* g, void* l) {
  __builtin_amdgcn_global_load_lds(
      (const __attribute__((address_space(1))) void*)(uintptr_t)g,
      (__attribute__((address_space(3))) void*)(uint32_t)(uintptr_t)l, 16, 0, 0);
}

// ---------- fp32 -> fp16 helpers (RNE via v_cvt_f16_f32) ----------
__device__ __forceinline__ uint16_t f16_rne(float x) {
  return __builtin_bit_cast(uint16_t, (_Float16)x);
}
__device__ __forceinline__ float f16_up(uint16_t h) {
  return (float)__builtin_bit_cast(_Float16, h);
}

__device__ __forceinline__ float exp2_fast(float x) {
#if __has_builtin(__builtin_amdgcn_exp2f)
  return __builtin_amdgcn_exp2f(x);
#else
  return exp2f(x);
#endif
}
// v_cvt_pkrtz_f16_f32: round-toward-zero => overflow SATURATES to 65504
// (never inf) -- this makes an explicit pre-clamp unnecessary.
__device__ __forceinline__ uint32_t pk_f16(float a, float b) {
#if __has_builtin(__builtin_amdgcn_cvt_pkrtz)
  return __builtin_bit_cast(uint32_t, __builtin_amdgcn_cvt_pkrtz(a, b));
#else
  union { uint16_t u[2]; uint32_t w; } r;
  r.u[0] = f16_rne(fminf(a, 65504.0f));
  r.u[1] = f16_rne(fminf(b, 65504.0f));
  return r.w;
#endif
}

// raw workgroup barrier: LDS-visibility only (lgkmcnt(0)), NO vmcnt drain --
// in-flight global prefetch loads survive the barrier; their consumption is
// enforced by the hardware's counted vmcnt at the register use site.
__device__ __forceinline__ void lds_barrier() {
  asm volatile("s_waitcnt lgkmcnt(0)" ::: "memory");
  __builtin_amdgcn_sched_barrier(0);
  __builtin_amdgcn_s_barrier();
  __builtin_amdgcn_sched_barrier(0);
}

// XOR-swizzled LDS index for 64-elem (128B) rows: conflict-free (r5-verified).
__device__ __forceinline__ int swz(int row, int col) {
  return row * 64 + ((((col >> 3) + row) & 7) << 3) + (col & 7);
}

// ---------- fused elementwise fp16 split pre-pass ----------
struct SplitArgs {
  const float* src[4];
  uint16_t* hi[4];
  uint16_t* lo[4];  // nullptr -> hi-only
  int n4;
};
__global__ void split_multi(SplitArgs a) {
  const int z = blockIdx.y;
  int i = blockIdx.x * 256 + threadIdx.x;
  if (i >= a.n4) return;
  float4 x = ((const float4*)a.src[z])[i];
  ushort4 h;
  h.x = f16_rne(x.x);
  h.y = f16_rne(x.y);
  h.z = f16_rne(x.z);
  h.w = f16_rne(x.w);
  ((ushort4*)a.hi[z])[i] = h;
  if (a.lo[z]) {
    ushort4 l;
    l.x = f16_rne(x.x - f16_up(h.x));
    l.y = f16_rne(x.y - f16_up(h.y));
    l.z = f16_rne(x.z - f16_up(h.z));
    l.w = f16_rne(x.w - f16_up(h.w));
    ((ushort4*)a.lo[z])[i] = l;
  }
}

// ---------- fused QKV projection GEMM, fp16, BK=32, DBUF 32KB -------------
// BK=32 dbuf keeps 3 blocks/CU (R5 lesson: dbuf must not cost residency).
// Counted vmcnt(4) keeps next tile's loads in flight across the barrier;
// vmcnt(0) only on the last K-step. 4-unit permutation: conflicts == 0 (R3).
// z=0 epilogue pre-scales Q by 1/8*log2(e) so attn's exp2 needs no mul.
struct QKVArgs {
  const uint16_t* Ah[3];
  const uint16_t* Bh[3];
  const float* bias[3];
  uint16_t* oH[3];
  uint16_t* oL[3];  // nullptr -> hi-only
};

__global__ __launch_bounds__(256, 3) void gemm_qkv(QKVArgs args) {
  __shared__ uint16_t lds[2][2][128][32];  // [dbuf][A/B] (32 KB)
  const int K = 1024;
  const int tid = threadIdx.x;
  const int wv = tid >> 6, lane = tid & 63;
  const int lm = lane & 15, g = lane >> 4;
  const int wm = (wv & 1) * 64, wn = (wv >> 1) * 64;
  const int z = blockIdx.z;
  const bool isT = (z == 2);
  const int t = blockIdx.x + 8 * blockIdx.y;
  const int kx = t & 7, j = t >> 3;
  const int sx = (j & 3) | ((kx & 1) << 2);
  const int sy = (j >> 2) | ((kx >> 1) << 3);
  const int gm0 = (isT ? sx : sy) * 128;
  const int gn0 = (isT ? sy : sx) * 128;

  const uint16_t* base[2] = {args.Ah[z] + (size_t)gm0 * K,
                             args.Bh[z] + (size_t)gn0 * K};
  const int rl = lane >> 2;                            // row within 16-row chunk
  const int scl = (((lane & 3) - (rl >> 1)) & 3) * 8;  // staging source unit
  const int ucol = ((g + (lm >> 1)) & 3) * 8;          // frag read unit

  f32x4 acc[4][4];
#pragma unroll
  for (int a = 0; a < 4; ++a)
#pragma unroll
    for (int b = 0; b < 4; ++b) acc[a][b] = (f32x4)0.0f;

  // prologue: stage K-step 0 into buf 0 (16 chunks of 1KB; 4 per wave)
#pragma unroll
  for (int jj = 0; jj < 4; ++jj) {
    const int c = wv + 4 * jj;
    const int p = c >> 3, r16 = (c & 7) * 16;
    gld_lds16(base[p] + (size_t)(r16 + rl) * K + 0 + scl, &lds[0][p][r16][0]);
  }

#pragma unroll 1
  for (int ti = 0; ti < 32; ++ti) {
    const int cur = ti & 1;
    if (ti + 1 < 32) {
      const int kt = (ti + 1) * 32;
#pragma unroll
      for (int jj = 0; jj < 4; ++jj) {
        const int c = wv + 4 * jj;
        const int p = c >> 3, r16 = (c & 7) * 16;
        gld_lds16(base[p] + (size_t)(r16 + rl) * K + kt + scl,
                  &lds[cur ^ 1][p][r16][0]);
      }
      asm volatile("s_waitcnt vmcnt(4)" ::: "memory");
    } else {
      asm volatile("s_waitcnt vmcnt(0)" ::: "memory");
    }
    __builtin_amdgcn_sched_barrier(0);
    __builtin_amdgcn_s_barrier();
    __builtin_amdgcn_sched_barrier(0);
    hfrag_t af[4];
#pragma unroll
    for (int mf = 0; mf < 4; ++mf) {
      af[mf] = *(const hfrag_t*)&lds[cur][0][wm + mf * 16 + lm][ucol];
    }
#pragma unroll
    for (int nf = 0; nf < 4; ++nf) {
      hfrag_t bhf = *(const hfrag_t*)&lds[cur][1][wn + nf * 16 + lm][ucol];
#pragma unroll
      for (int mf = 0; mf < 4; ++mf) {
        acc[mf][nf] = mfma16h(af[mf], bhf, acc[mf][nf]);
      }
    }
    __builtin_amdgcn_sched_barrier(0);
    __builtin_amdgcn_s_barrier();
    __builtin_amdgcn_sched_barrier(0);
  }
  const float* bias = args.bias[z];
  uint16_t* oH = args.oH[z];
  uint16_t* oL = args.oL[z];
  const float kQScale = 0.18033688f;  // 1/8 * log2(e): pre-scale Q for exp2
#pragma unroll
  for (int mf = 0; mf < 4; ++mf) {
#pragma unroll
    for (int nf = 0; nf < 4; ++nf) {
      const int col = gn0 + wn + nf * 16 + lm;
#pragma unroll
      for (int i = 0; i < 4; ++i) {
        const int row = gm0 + wm + mf * 16 + g * 4 + i;
        float v = acc[mf][nf][i] + (isT ? bias[row] : bias[col]);
        if (z == 0) v *= kQScale;
        uint16_t h = f16_rne(v);
        size_t addr;
        if (!isT) {
          addr = ((size_t)((row >> 11) * 16 + (col >> 6)) * 2048 + (row & 2047)) * 64 +
                 (col & 63);
        } else {
          addr = ((size_t)((col >> 11) * 1024 + row)) * 2048 + (col & 2047);
        }
        oH[addr] = h;
        if (oL) oL[addr] = f16_rne(v - f16_up(h));
      }
    }
  }
}

// ---------- O projection: fp16, BK=64, double-buffered, fp32 out ----------
__global__ __launch_bounds__(256, 2) void gemm_o(
    const uint16_t* __restrict__ Ah, const uint16_t* __restrict__ Bh,
    const float* __restrict__ bias, float* __restrict__ out) {
  const int K = 1024, N = 1024;
  __shared__ uint16_t ldsA[2][64][64];   // 16 KB
  __shared__ uint16_t ldsB[2][128][64];  // 32 KB
  const int tid = threadIdx.x;
  const int wv = tid >> 6, lane = tid & 63;
  const int lm = lane & 15, g = lane >> 4;
  const int wm = (wv & 1) * 32, wn = (wv >> 1) * 64;
  const int t = blockIdx.x + 8 * blockIdx.y;
  const int kx = t & 7, j = t >> 3;
  const int sx = (j & 3) | ((kx & 1) << 2);
  const int sy = (j >> 2) | ((kx >> 1) << 4);
  const int gm0 = sy * 64, gn0 = sx * 128;
  const uint16_t* baseA = Ah + (size_t)gm0 * K;
  const uint16_t* baseB = Bh + (size_t)gn0 * K;
  const int rl8 = lane >> 3;
  const int scl = (((lane & 7) - rl8) & 7) * 8;

  f32x4 acc[2][4];
#pragma unroll
  for (int a = 0; a < 2; ++a)
#pragma unroll
    for (int b = 0; b < 4; ++b) acc[a][b] = (f32x4)0.0f;

  // prologue: stage tile 0 into buf 0
#pragma unroll
  for (int jj = 0; jj < 6; ++jj) {
    const int c = wv + 4 * jj;  // 24 chunks: 8 A + 16 B
    if (c < 8) {
      gld_lds16(baseA + (size_t)(c * 8 + rl8) * K + 0 + scl, &ldsA[0][c * 8][0]);
    } else {
      const int b = c - 8;
      gld_lds16(baseB + (size_t)(b * 8 + rl8) * K + 0 + scl, &ldsB[0][b * 8][0]);
    }
  }

#pragma unroll 1
  for (int ti = 0; ti < 16; ++ti) {
    const int cur = ti & 1;
    if (ti + 1 < 16) {
      const int kt = (ti + 1) * 64;
#pragma unroll
      for (int jj = 0; jj < 6; ++jj) {
        const int c = wv + 4 * jj;
        if (c < 8) {
          gld_lds16(baseA + (size_t)(c * 8 + rl8) * K + kt + scl,
                    &ldsA[cur ^ 1][c * 8][0]);
        } else {
          const int b = c - 8;
          gld_lds16(baseB + (size_t)(b * 8 + rl8) * K + kt + scl,
                    &ldsB[cur ^ 1][b * 8][0]);
        }
      }
      asm volatile("s_waitcnt vmcnt(6)" ::: "memory");
    } else {
      asm volatile("s_waitcnt vmcnt(0)" ::: "memory");
    }
    __builtin_amdgcn_sched_barrier(0);
    __builtin_amdgcn_s_barrier();
    __builtin_amdgcn_sched_barrier(0);
#pragma unroll
    for (int ks = 0; ks < 2; ++ks) {
      const int uc = ((ks * 4 + g + lm) & 7) * 8;
      hfrag_t af[2];
#pragma unroll
      for (int mf = 0; mf < 2; ++mf) {
        af[mf] = *(const hfrag_t*)&ldsA[cur][wm + mf * 16 + lm][uc];
      }
#pragma unroll
      for (int nf = 0; nf < 4; ++nf) {
        hfrag_t bhf = *(const hfrag_t*)&ldsB[cur][wn + nf * 16 + lm][uc];
#pragma unroll
        for (int mf = 0; mf < 2; ++mf) {
          acc[mf][nf] = mfma16h(af[mf], bhf, acc[mf][nf]);
        }
      }
    }
    __builtin_amdgcn_sched_barrier(0);
    __builtin_amdgcn_s_barrier();
    __builtin_amdgcn_sched_barrier(0);
  }
#pragma unroll
  for (int mf = 0; mf < 2; ++mf)
#pragma unroll
    for (int nf = 0; nf < 4; ++nf) {
      const int col = gn0 + wn + nf * 16 + lm;
#pragma unroll
      for (int i = 0; i < 4; ++i) {
        const int row = gm0 + wm + mf * 16 + g * 4 + i;
        out[(size_t)row * N + col] = acc[mf][nf][i] + bias[col];
      }
    }
}

// ---------- fused attention v12: raw lgkm-only barriers --------------------
// __syncthreads drains vmcnt(0): it forced the next-iter K prefetch (issued
// after barrier-1, needed only at next loop-top) to COMPLETE at barrier-2,
// exposing its ~500cy latency every iteration. lds_barrier() waits only
// lgkmcnt(0) (LDS visibility -- the only cross-wave obligation); in-flight
// K loads now span the whole iteration, consumption hw-enforced by counted
// vmcnt at the ds_write that uses the registers.
__global__ __launch_bounds__(256, 2) void attn_kernel(
    const uint16_t* __restrict__ Qh,
    const uint16_t* __restrict__ Kh,
    const uint16_t* __restrict__ Vh,
    float* __restrict__ opart, float* __restrict__ lpart) {
  __shared__ uint16_t kt[4096];  // K tile [kv 64][hd 64] hi, swizzled (8 KB)
  __shared__ uint16_t vt[4096];  // V^T tile [d 64][kv 64] hi, swizzled (8 KB)
  __shared__ uint16_t pp[8192];  // P (fp16) [qrow 128][kv 64], swizzled (16 KB)
  const int tid = threadIdx.x;
  const int wave = tid >> 6, lane = tid & 63;
  const int lm = lane & 15, g = lane >> 4;
  const int linear = blockIdx.x + 32 * blockIdx.y;
  const int bh = (linear & 7) + 8 * (linear >> 8);
  const int qt = (linear >> 3) & 15;
  const int half = (linear >> 7) & 1;
  const int kvh = half * 1024;
  const size_t base = (size_t)bh * 131072;
  const int q0 = qt * 128 + wave * 32;

  hfrag_t qf[2][2];  // [b(q-16-tile)][ks]  (Q pre-scaled by 1/8*log2(e))
#pragma unroll
  for (int b = 0; b < 2; ++b) {
    const size_t rb = base + (size_t)(q0 + b * 16 + lm) * 64 + g * 8;
    qf[b][0] = *(const hfrag_t*)(Qh + rb);
    qf[b][1] = *(const hfrag_t*)(Qh + rb + 32);
  }
  f32x4 oacc[2][4];
  f32x4 lacc[2];
#pragma unroll
  for (int mf = 0; mf < 2; ++mf) {
    lacc[mf] = (f32x4)0.0f;
#pragma unroll
    for (int nf = 0; nf < 4; ++nf) oacc[mf][nf] = (f32x4)0.0f;
  }
  short8 ones_s = (short8)(short)0x3C00;  // fp16 1.0
  hfrag_t ones = __builtin_bit_cast(hfrag_t, ones_s);

  const int sr = tid >> 3;       // 0..31
  const int sc = (tid & 7) * 8;  // 0..56

  uint4 kr0, kr1, vr0, vr1;
  {
    const size_t ka = base + (size_t)(kvh + sr) * 64 + sc;
    kr0 = *(const uint4*)(Kh + ka);
    kr1 = *(const uint4*)(Kh + ka + 2048);
  }

#pragma unroll 1
  for (int it = 0; it < 16; ++it) {
    const int kv0 = kvh + it * 64;
    *(uint4*)&kt[swz(sr, sc)] = kr0;
    *(uint4*)&kt[swz(sr + 32, sc)] = kr1;
    lds_barrier();  // barrier 1: K published; prev-iter vt/pp reads done
    {  // issue V loads AND next-K loads; both hidden by QK^T+softmax+PV
      const size_t va = base + (size_t)sr * 2048 + kv0 + sc;
      vr0 = *(const uint4*)(Vh + va);
      vr1 = *(const uint4*)(Vh + va + 65536);
    }
    if (it + 1 < 16) {
      const size_t ka = base + (size_t)(kv0 + 64 + sr) * 64 + sc;
      kr0 = *(const uint4*)(Kh + ka);
      kr1 = *(const uint4*)(Kh + ka + 2048);
    }
    f32x4 sct[4][2];
#pragma unroll
    for (int a = 0; a < 4; ++a)
#pragma unroll
      for (int b = 0; b < 2; ++b) sct[a][b] = (f32x4)0.0f;
    __builtin_amdgcn_s_setprio(1);
#pragma unroll
    for (int ks = 0; ks < 2; ++ks) {
#pragma unroll
      for (int a = 0; a < 4; ++a) {
        hfrag_t kfh = *(const hfrag_t*)&kt[swz(a * 16 + lm, ks * 32 + g * 8)];
#pragma unroll
        for (int b = 0; b < 2; ++b) {
          sct[a][b] = mfma16h(kfh, qf[b][ks], sct[a][b]);
        }
      }
    }
    __builtin_amdgcn_s_setprio(0);
#pragma unroll
    for (int a = 0; a < 4; ++a) {
#pragma unroll
      for (int b = 0; b < 2; ++b) {
        // no clamp: cvt_pkrtz saturates on overflow (RTZ -> 65504, not inf)
        float e0 = exp2_fast(sct[a][b][0]);
        float e1 = exp2_fast(sct[a][b][1]);
        float e2 = exp2_fast(sct[a][b][2]);
        float e3 = exp2_fast(sct[a][b][3]);
        uint2 pk;
        pk.x = pk_f16(e0, e1);
        pk.y = pk_f16(e2, e3);
        *(uint2*)&pp[swz(wave * 32 + b * 16 + lm, a * 16 + g * 4)] = pk;
      }
    }
    *(uint4*)&vt[swz(sr, sc)] = vr0;
    *(uint4*)&vt[swz(sr + 32, sc)] = vr1;
    lds_barrier();  // barrier 2: V/P published; K prefetch stays in flight
    __builtin_amdgcn_s_setprio(1);
#pragma unroll
    for (int ks = 0; ks < 2; ++ks) {
      hfrag_t pa[2];
#pragma unroll
      for (int mf = 0; mf < 2; ++mf) {
        pa[mf] = *(const hfrag_t*)&pp[swz(wave * 32 + mf * 16 + lm, ks * 32 + g * 8)];
        lacc[mf] = mfma16h(pa[mf], ones, lacc[mf]);
      }
#pragma unroll
      for (int nf = 0; nf < 4; ++nf) {
        hfrag_t vbh = *(const hfrag_t*)&vt[swz(nf * 16 + lm, ks * 32 + g * 8)];
#pragma unroll
        for (int mf = 0; mf < 2; ++mf) {
          oacc[mf][nf] = mfma16h(pa[mf], vbh, oacc[mf][nf]);
        }
      }
    }
    __builtin_amdgcn_s_setprio(0);
  }
  const int obase = (half * 32 + bh) * 2048;
#pragma unroll
  for (int mf = 0; mf < 2; ++mf) {
#pragma unroll
    for (int i = 0; i < 4; ++i) {
      const int qrow = qt * 128 + wave * 32 + mf * 16 + g * 4 + i;
      float* orow = opart + ((size_t)obase + qrow) * 64;
#pragma unroll
      for (int nf = 0; nf < 4; ++nf) orow[nf * 16 + lm] = oacc[mf][nf][i];
      if (lm == 0) lpart[obase + qrow] = lacc[mf][i];
    }
  }
}

// ---------- combine partials, normalize, emit fp16 O plane ----------
__global__ void combine_kernel(const float* __restrict__ opart,
                               const float* __restrict__ lpart,
                               uint16_t* __restrict__ oh) {
  const int idx = blockIdx.x * 256 + threadIdx.x;
  const float4 a = ((const float4*)opart)[idx];
  const float4 b = ((const float4*)(opart + 4194304))[idx];
  const int row = idx >> 4;
  const float linv = 1.0f / (lpart[row] + lpart[65536 + row]);
  const int bh = row >> 11, qq = row & 2047;
  const int bb = bh >> 4, hh = bh & 15;
  const size_t o = ((size_t)(bb * 2048 + qq)) * 1024 + hh * 64 + (idx & 15) * 4;
  ushort4 H;
  H.x = f16_rne((a.x + b.x) * linv);
  H.y = f16_rne((a.y + b.y) * linv);
  H.z = f16_rne((a.z + b.z) * linv);
  H.w = f16_rne((a.w + b.w) * linv);
  *(ushort4*)(oh + o) = H;
}

extern "C" void kernel_launch(void* const* d_in, const int* in_sizes, int n_in,
                              void* d_out, int out_size, void* d_ws, size_t ws_size,
                              hipStream_t stream) {
  const float* q = (const float*)d_in[0];
  const float* k = (const float*)d_in[1];
  const float* v = (const float*)d_in[2];
  const float* Wq = (const float*)d_in[3];
  const float* bq = (const float*)d_in[4];
  const float* Wk = (const float*)d_in[5];
  const float* bk = (const float*)d_in[6];
  const float* Wv = (const float*)d_in[7];
  const float* bv = (const float*)d_in[8];
  const float* Wo = (const float*)d_in[9];
  const float* bo = (const float*)d_in[10];

  const size_t NX = 4194304;  // B*S*H
  const size_t NW = 1048576;  // H*H
  uint16_t* p = (uint16_t*)d_ws;
  uint16_t* xqh = p; p += NX; uint16_t* xql = p; p += NX;  // xql unused
  uint16_t* xkh = p; p += NX; uint16_t* xkl = p; p += NX;  // xkl unused
  uint16_t* xvh = p; p += NX; uint16_t* xvl = p; p += NX;  // xvl unused
  uint16_t* wqh = p; p += NW; uint16_t* wql = p; p += NW;  // wql unused
  uint16_t* wkh = p; p += NW; uint16_t* wkl = p; p += NW;  // wkl unused
  uint16_t* wvh = p; p += NW; uint16_t* wvl = p; p += NW;  // wvl unused
  uint16_t* woh = p; p += NW; uint16_t* wol = p; p += NW;  // wol unused
  uint16_t* qph = p; p += NX; uint16_t* qpl = p; p += NX;  // qpl unused
  uint16_t* kph = p; p += NX; uint16_t* kpl = p; p += NX;  // kpl unused
  uint16_t* vth = p; p += NX; uint16_t* vtl = p; p += NX;  // vtl unused
  uint16_t* oh = xqh;  // alias: xq consumed before combine writes o
  float* opart = (float*)xkh;          // 33.6 MB over xkh..xvl (dead after qkv)
  float* lpart = opart + 2 * 4194304;  // 0.5 MB into wq region (dead after qkv)

  SplitArgs sx;
  sx.src[0] = q;  sx.hi[0] = xqh; sx.lo[0] = nullptr;
  sx.src[1] = k;  sx.hi[1] = xkh; sx.lo[1] = nullptr;
  sx.src[2] = v;  sx.hi[2] = xvh; sx.lo[2] = nullptr;
  sx.src[3] = nullptr; sx.hi[3] = nullptr; sx.lo[3] = nullptr;
  sx.n4 = (int)(NX / 4);
  split_multi<<<dim3((unsigned)(NX / 4 / 256), 3), 256, 0, stream>>>(sx);

  SplitArgs sw;
  sw.src[0] = Wq; sw.hi[0] = wqh; sw.lo[0] = nullptr;
  sw.src[1] = Wk; sw.hi[1] = wkh; sw.lo[1] = nullptr;
  sw.src[2] = Wv; sw.hi[2] = wvh; sw.lo[2] = nullptr;
  sw.src[3] = Wo; sw.hi[3] = woh; sw.lo[3] = nullptr;
  sw.n4 = (int)(NW / 4);
  split_multi<<<dim3((unsigned)(NW / 4 / 256), 4), 256, 0, stream>>>(sw);

  QKVArgs qa;
  qa.Ah[0] = xqh; qa.Bh[0] = wqh; qa.bias[0] = bq; qa.oH[0] = qph; qa.oL[0] = nullptr;
  qa.Ah[1] = xkh; qa.Bh[1] = wkh; qa.bias[1] = bk; qa.oH[1] = kph; qa.oL[1] = nullptr;
  qa.Ah[2] = wvh; qa.Bh[2] = xvh; qa.bias[2] = bv; qa.oH[2] = vth; qa.oL[2] = nullptr;
  gemm_qkv<<<dim3(8, 32, 3), 256, 0, stream>>>(qa);

  attn_kernel<<<dim3(32, 32), 256, 0, stream>>>(qph, kph, vth, opart, lpart);
  combine_kernel<<<4096, 256, 0, stream>>>(opart, lpart, oh);

  gemm_o<<<dim3(8, 64), 256, 0, stream>>>(oh, woh, bo, (float*)d_out);
}